// Round 9
// baseline (478.632 us; speedup 1.0000x reference)
//
#include <hip/hip_runtime.h>
#include <cstdint>
#include <cstddef>

#define NB 16
#define NC 84
#define NA 33600
#define NCLS 80
#define TOPK 1024
#define NBIN 8192        // coarse bins: mono_u32 >> 19
#define CANDCAP 8192
#define SCORE_THR 0.005f
#define IOU_THR 0.5f

// ---- 64-bit sort key: (monotonic fp32) << 32 | ~index ----------------------
// Larger key == (higher score, then lower index) == jax.lax.top_k order.
__device__ __forceinline__ unsigned mono_u32(float f) {
    unsigned u = __float_as_uint(f);
    return (u & 0x80000000u) ? ~u : (u | 0x80000000u);
}
__device__ __forceinline__ float key_val(uint64_t k) {
    unsigned u = (unsigned)(k >> 32);
    u = (u & 0x80000000u) ? (u & 0x7FFFFFFFu) : ~u;
    return __uint_as_float(u);
}
__device__ __forceinline__ int key_idx(uint64_t k) {
    return (int)(~(uint32_t)(k & 0xFFFFFFFFu));
}
__device__ __forceinline__ uint64_t readlane_u64(uint64_t v, int lane) {
    unsigned lo = __builtin_amdgcn_readlane((unsigned)(v & 0xFFFFFFFFULL), lane);
    unsigned hi = __builtin_amdgcn_readlane((unsigned)(v >> 32), lane);
    return ((uint64_t)hi << 32) | (uint64_t)lo;
}
__device__ __forceinline__ uint64_t shfl_xor_u64(uint64_t v, int m) {
    return (uint64_t)__shfl_xor((unsigned long long)v, m, 64);
}

// ---- K1: max/argmax over 80 classes (float4) + LDS-private histogram -------
// grid (33, NB): block handles 1024 anchors (256 float4) of one batch.
__global__ __launch_bounds__(256) void score_hist_kernel(const float* __restrict__ x,
                                                         float* __restrict__ sval,
                                                         int* __restrict__ cid,
                                                         unsigned* __restrict__ hist) {
    __shared__ unsigned h[NBIN];
    const int t = threadIdx.x;
    const int b = blockIdx.y;
    for (int i = t; i < NBIN; i += 256) h[i] = 0;
    __syncthreads();
    int q = blockIdx.x * 256 + t;                 // float4 index within batch
    if (q < NA / 4) {
        const float4* p = (const float4*)(x + (size_t)b * NC * NA + (size_t)4 * NA) + q;
        float4 best = p[0];
        int4 bc = {0, 0, 0, 0};
#pragma unroll 8
        for (int c = 1; c < NCLS; ++c) {
            float4 v = p[(size_t)c * (NA / 4)];
            if (v.x > best.x) { best.x = v.x; bc.x = c; }
            if (v.y > best.y) { best.y = v.y; bc.y = c; }
            if (v.z > best.z) { best.z = v.z; bc.z = c; }
            if (v.w > best.w) { best.w = v.w; bc.w = c; }
        }
        float4 s;
        s.x = (best.x > SCORE_THR) ? best.x : -INFINITY;
        s.y = (best.y > SCORE_THR) ? best.y : -INFINITY;
        s.z = (best.z > SCORE_THR) ? best.z : -INFINITY;
        s.w = (best.w > SCORE_THR) ? best.w : -INFINITY;
        ((float4*)sval)[(size_t)b * (NA / 4) + q] = s;
        ((int4*)cid)[(size_t)b * (NA / 4) + q] = bc;
        atomicAdd(&h[mono_u32(s.x) >> 19], 1u);
        atomicAdd(&h[mono_u32(s.y) >> 19], 1u);
        atomicAdd(&h[mono_u32(s.z) >> 19], 1u);
        atomicAdd(&h[mono_u32(s.w) >> 19], 1u);
    }
    __syncthreads();
    unsigned* gh = hist + (size_t)b * NBIN;
    for (int i = t; i < NBIN; i += 256) {
        unsigned v = h[i];
        if (v) atomicAdd(&gh[i], v);
    }
}

// ---- K2: per-block cutbin recompute + compact slice ------------------------
// grid (16, NB): each block scans the (L2-hot) hist, then compacts 2100 anchors.
__global__ __launch_bounds__(256) void select_kernel(const float* __restrict__ sval,
                                                     const unsigned* __restrict__ hist,
                                                     uint64_t* __restrict__ cand,
                                                     unsigned* __restrict__ cnt) {
    __shared__ unsigned csum[256];
    __shared__ unsigned scut, lc, lbase;
    __shared__ uint64_t cbuf[2112];
    const int t = threadIdx.x;
    const int b = blockIdx.y;
    const int sl = blockIdx.x;

    const unsigned* gh = hist + (size_t)b * NBIN;
    unsigned cnts[32];
    unsigned local = 0;
#pragma unroll
    for (int q = 0; q < 32; ++q) {
        cnts[q] = gh[NBIN - 1 - (t * 32 + q)];
        local += cnts[q];
    }
    csum[t] = local;
    __syncthreads();
    for (int off = 1; off < 256; off <<= 1) {
        unsigned v = (t >= off) ? csum[t - off] : 0u;
        __syncthreads();
        csum[t] += v;
        __syncthreads();
    }
    unsigned incl = csum[t], excl = incl - local;
    if (excl < TOPK && incl >= TOPK) {
        unsigned cum = excl;
#pragma unroll
        for (int q = 0; q < 32; ++q) {
            if (cum + cnts[q] >= TOPK) { scut = (unsigned)(NBIN - 1 - (t * 32 + q)); break; }
            cum += cnts[q];
        }
    }
    if (t == 0) lc = 0;
    __syncthreads();
    unsigned cb = scut;

    int a0 = sl * (NA / 16);
    const float* sv = sval + (size_t)b * NA;
    for (int a = a0 + t; a < a0 + NA / 16; a += 256) {
        unsigned u = mono_u32(sv[a]);
        if ((u >> 19) >= cb) {
            unsigned pos = atomicAdd(&lc, 1u);
            cbuf[pos] = ((uint64_t)u << 32) | (uint32_t)(~(uint32_t)a);
        }
    }
    __syncthreads();
    if (t == 0) lbase = lc ? atomicAdd(&cnt[b * 64], lc) : 0u;
    __syncthreads();
    for (unsigned i = t; i < lc; i += 256) {
        unsigned p = lbase + i;
        if (p < CANDCAP) cand[((size_t)b << 13) + p] = cbuf[i];
    }
}

// ---- K3: exact top-1024 by rank-counting + fused box/cid gather ------------
// grid (4, NB). Keys unique -> ranks unique -> output bit-identical to top_k.
__global__ __launch_bounds__(256) void rank_gather_kernel(const float* __restrict__ x,
                                                          const int* __restrict__ cid,
                                                          const uint64_t* __restrict__ cand,
                                                          const unsigned* __restrict__ cnt,
                                                          float* __restrict__ tval,
                                                          float* __restrict__ bx1, float* __restrict__ by1,
                                                          float* __restrict__ bx2, float* __restrict__ by2,
                                                          float* __restrict__ barr, int* __restrict__ tcid) {
    __shared__ uint64_t lk[CANDCAP];   // 64 KB
    const int t = threadIdx.x;
    const int b = blockIdx.y;
    const int sl = blockIdx.x;
    unsigned C = cnt[b * 64];
    if (C > CANDCAP) C = CANDCAP;
    const uint64_t* cb = cand + ((size_t)b << 13);
    for (unsigned i = t; i < C; i += 256) lk[i] = cb[i];
    __syncthreads();

    const int base = b << 10;
    const float* xb = x + (size_t)b * NC * NA;
    for (int i0 = sl * 256 + t; i0 < (int)C; i0 += 1024) {
        uint64_t my = lk[i0];
        unsigned rank = 0;
        int j = 0;
        for (; j + 4 <= (int)C; j += 4) {
            rank += (lk[j] > my);
            rank += (lk[j + 1] > my);
            rank += (lk[j + 2] > my);
            rank += (lk[j + 3] > my);
        }
        for (; j < (int)C; ++j) rank += (lk[j] > my);
        if (rank < TOPK) {
            int idx = key_idx(my);
            tval[base + rank] = key_val(my);
            float x1 = xb[idx], y1 = xb[NA + idx], x2 = xb[2 * NA + idx], y2 = xb[3 * NA + idx];
            bx1[base + rank] = x1; by1[base + rank] = y1;
            bx2[base + rank] = x2; by2[base + rank] = y2;
            barr[base + rank] = (x2 - x1) * (y2 - y1);
            tcid[base + rank] = cid[b * NA + idx];
        }
    }
}

// ---- K4: suppression bit-matrix + last-block-fused serial sweep ------------
// grid (64, NB): block builds 16 rows of M. Last finishing block per batch
// (agent-scope done counter, 256B-padded) runs the sweep.
// Sweep = block-diagonal register recurrence: lane i holds diagonal word
// D[q]=M[64q+i].word_q; per-row step is readlane + 3 SALU ops (no LDS, no
// cross-lane of live state). Incoming rem per block via lane-masked column
// loads + one shfl_xor OR-tree (off the serial chain).
#define LDSPAD(j) ((j) + ((j) >> 6))
__global__ __launch_bounds__(256) void mask_sweep_kernel(const float* __restrict__ tval,
                                                         const int* __restrict__ tcid,
                                                         const float* __restrict__ bx1,
                                                         const float* __restrict__ by1,
                                                         const float* __restrict__ bx2,
                                                         const float* __restrict__ by2,
                                                         const float* __restrict__ barr,
                                                         uint64_t* __restrict__ M,
                                                         unsigned* __restrict__ done,
                                                         float* __restrict__ out) {
    __shared__ float sx1[TOPK + 16], sy1[TOPK + 16], sx2[TOPK + 16], sy2[TOPK + 16], sar[TOPK + 16];
    __shared__ unsigned sdone;
    const int t = threadIdx.x;
    const int b = blockIdx.y;
    const int base = b << 10;

    for (int j = t; j < TOPK; j += 256) {
        int ji = LDSPAD(j);
        sx1[ji] = bx1[base + j]; sy1[ji] = by1[base + j];
        sx2[ji] = bx2[base + j]; sy2[ji] = by2[base + j];
        sar[ji] = barr[base + j];
    }
    __syncthreads();

    {
        int w = t & 15;
        int r = (blockIdx.x << 4) + (t >> 4);
        int ri = LDSPAD(r);
        float ix1 = sx1[ri], iy1 = sy1[ri], ix2 = sx2[ri], iy2 = sy2[ri], ia = sar[ri];
        uint64_t m = 0;
#pragma unroll 8
        for (int jj = 0; jj < 64; ++jj) {
            int j = (w << 6) + jj;
            int ji = w * 65 + jj;
            float ltx = fmaxf(ix1, sx1[ji]);
            float lty = fmaxf(iy1, sy1[ji]);
            float rbx = fminf(ix2, sx2[ji]);
            float rby = fminf(iy2, sy2[ji]);
            float ww = fmaxf(rbx - ltx, 0.0f);
            float hh = fmaxf(rby - lty, 0.0f);
            float inter = ww * hh;
            float uni = ia + sar[ji] - inter;      // same op order as reference
            float iou = inter / fmaxf(uni, 1e-9f);
            if (j > r && iou > IOU_THR) m |= (1ULL << jj);
        }
        M[(((size_t)(base + r)) << 4) + w] = m;
    }

    // ---- publish, then elect last block (done padded: 1 counter / 256 B) ----
    __syncthreads();
    __threadfence();
    if (t == 0)
        sdone = __hip_atomic_fetch_add(&done[b * 64], 1u, __ATOMIC_ACQ_REL, __HIP_MEMORY_SCOPE_AGENT);
    __syncthreads();
    if (sdone != 63) return;

    // ---- serial greedy sweep (wave 0 only) ----
    if (t >= 64) return;
    const int l = t;

    float tvl[16];
    uint64_t V[16], D[16], K[16];
#pragma unroll
    for (int q = 0; q < 16; ++q) {
        tvl[q] = tval[base + (q << 6) + l];
        V[q] = __ballot(tvl[q] > SCORE_THR);
        D[q] = M[(((size_t)(base + (q << 6) + l)) << 4) + q];   // diagonal word
    }

#pragma unroll
    for (int q = 0; q < 16; ++q) {
        // incoming rem word q = OR over kept rows of earlier blocks
        uint64_t contrib = 0;
#pragma unroll
        for (int p = 0; p < 16; ++p) {
            if (p < q) {
                uint64_t cw = M[(((size_t)(base + (p << 6) + l)) << 4) + q];
                contrib |= (((K[p] >> l) & 1ULL) ? cw : 0ULL);
            }
        }
#pragma unroll
        for (int s = 1; s < 64; s <<= 1) contrib |= shfl_xor_u64(contrib, s);
        uint64_t rem = contrib;            // wave-uniform
        uint64_t vq = V[q];
        uint64_t Kq = 0;
        for (int i = 0; i < 64; ++i) {     // pure scalar chain per iteration
            uint64_t row = readlane_u64(D[q], i);
            uint64_t bit = 1ULL << i;
            bool kept = ((vq & bit) != 0ULL) && ((rem & bit) == 0ULL);
            rem |= kept ? row : 0ULL;
            Kq |= kept ? bit : 0ULL;
        }
        K[q] = Kq;
    }

    // ---- epilogue ----
#pragma unroll
    for (int s = 0; s < 16; ++s) {
        bool kp = (K[s] >> l) & 1ULL;
        int k = (s << 6) + l;
        float x1 = bx1[base + k], y1 = by1[base + k];
        float x2 = bx2[base + k], y2 = by2[base + k];
        float* po = out + ((size_t)(base + k)) * 6;
        po[0] = kp ? x1 : 0.0f;
        po[1] = kp ? y1 : 0.0f;
        po[2] = kp ? x2 : 0.0f;
        po[3] = kp ? y2 : 0.0f;
        po[4] = kp ? tvl[s] : 0.0f;
        po[5] = kp ? (float)tcid[base + k] : 0.0f;
        out[(size_t)NB * TOPK * 6 + base + k] = kp ? 1.0f : 0.0f;
    }
}

extern "C" void kernel_launch(void* const* d_in, const int* in_sizes, int n_in,
                              void* d_out, int out_size, void* d_ws, size_t ws_size,
                              hipStream_t stream) {
    const float* x = (const float*)d_in[0];
    float* out = (float*)d_out;
    char* ws = (char*)d_ws;

    size_t off = 0;
    auto alloc = [&](size_t bytes) { void* p = ws + off; off = (off + bytes + 255) & ~(size_t)255; return p; };
    float*    sval    = (float*)alloc((size_t)NB * NA * 4);
    int*      cid     = (int*)alloc((size_t)NB * NA * 4);
    // hist + cnt + done contiguous -> one memset
    unsigned* hist    = (unsigned*)alloc((size_t)NB * NBIN * 4);     // 512 KB
    unsigned* cnt     = (unsigned*)alloc((size_t)NB * 64 * 4);       // 4 KB (256B stride/batch)
    unsigned* done    = (unsigned*)alloc((size_t)NB * 64 * 4);       // 4 KB (256B stride/batch)
    uint64_t* cand    = (uint64_t*)alloc((size_t)NB * CANDCAP * 8);
    float*    tval    = (float*)alloc((size_t)NB * TOPK * 4);
    float*    bx1     = (float*)alloc((size_t)NB * TOPK * 4);
    float*    by1     = (float*)alloc((size_t)NB * TOPK * 4);
    float*    bx2     = (float*)alloc((size_t)NB * TOPK * 4);
    float*    by2     = (float*)alloc((size_t)NB * TOPK * 4);
    float*    barr    = (float*)alloc((size_t)NB * TOPK * 4);
    int*      tcid    = (int*)alloc((size_t)NB * TOPK * 4);
    uint64_t* M       = (uint64_t*)alloc((size_t)NB * TOPK * 16 * 8);

    size_t zbytes = (size_t)NB * NBIN * 4 + (size_t)NB * 64 * 4 * 2;
    hipMemsetAsync(hist, 0, zbytes, stream);

    score_hist_kernel<<<dim3(33, NB), 256, 0, stream>>>(x, sval, cid, hist);
    select_kernel<<<dim3(16, NB), 256, 0, stream>>>(sval, hist, cand, cnt);
    rank_gather_kernel<<<dim3(4, NB), 256, 0, stream>>>(x, cid, cand, cnt, tval,
                                                        bx1, by1, bx2, by2, barr, tcid);
    mask_sweep_kernel<<<dim3(64, NB), 256, 0, stream>>>(tval, tcid, bx1, by1, bx2, by2,
                                                        barr, M, done, out);
}